// Round 5
// baseline (25.084 us; speedup 1.0000x reference)
//
#include <hip/hip_runtime.h>
#include <hip/hip_bf16.h>

// Tree-MLP via bf16 MFMA (16x16x32), fp32 accumulate. v5: occupancy-focused.
//  - swapped product D[n][m] = W^T X^T per node; D layout (col=sample, row=4g+r)
//    feeds the next layer's B fragment under k-map k(g,j)=4g+j | 16+4g+(j-4).
//  - one variable vs v3/v4: 4 waves/SIMD (16/CU) instead of 3. VGPR <= 128
//    guaranteed spill-free by DFS evaluation (<=2 live acc per level) and
//    bf16-packed biases (14 regs, unpacked per tile).
//  - TPI=1 (v4 showed TPI=2 neutral), 2-deep prefetch, nt stores only.
//  - grid 1024 = exactly 4 blocks/CU resident, 8 tiles/wave, no tail.

typedef __attribute__((ext_vector_type(8))) short bf16x8;   // 8 bf16 = 4 VGPRs
typedef __attribute__((ext_vector_type(4))) short bf16x4;   // 4 bf16 = 2 VGPRs
typedef __attribute__((ext_vector_type(4))) float f32x4;    // 4 fp32

__device__ __forceinline__ short bfr(float f) {
  return (short)__builtin_bit_cast(unsigned short, __float2bfloat16(f));
}
__device__ __forceinline__ float bf2f(short s) {
  unsigned u = ((unsigned)(unsigned short)s) << 16;
  return __builtin_bit_cast(float, u);
}
__device__ __forceinline__ float relu_(float a) { return fmaxf(a, 0.0f); }
__device__ __forceinline__ f32x4 unpk(bf16x4 p) {
  f32x4 c;
#pragma unroll
  for (int r = 0; r < 4; ++r) c[r] = bf2f(p[r]);
  return c;
}

__global__ __launch_bounds__(256, 4) void tree_mlp_mfma5(
    const float* __restrict__ x,
    const float* __restrict__ W1, const float* __restrict__ b1,
    const float* __restrict__ W2, const float* __restrict__ b2,
    const float* __restrict__ W3, const float* __restrict__ b3,
    const float* __restrict__ W4, const float* __restrict__ b4,
    float* __restrict__ out, int ntiles) {
  const int lane = threadIdx.x & 63;
  const int n = lane & 15;   // output feature row / sample col
  const int g = lane >> 4;   // lane group 0..3

  const int wpb = blockDim.x >> 6;
  const int gw = blockIdx.x * wpb + (threadIdx.x >> 6);
  const int nw = gridDim.x * wpb;

  // ---------------- weight fragments (loop-invariant, 60 VGPR) -------------
  bf16x8 w1f[8];
#pragma unroll
  for (int i = 0; i < 8; ++i) {
    bf16x8 f;
#pragma unroll
    for (int j = 0; j < 8; ++j) f[j] = (short)0;
#pragma unroll
    for (int j = 0; j < 4; ++j) {
      int k = 4 * g + j;
      float v = 0.0f;
      if (k == 2 * i)     v = W1[i * 32 + n];
      if (k == 2 * i + 1) v = W1[i * 32 + 16 + n];
      f[j] = bfr(v);
    }
    if (g == 0) f[4] = bfr(b1[i * 16 + n]);   // L1 bias in k==16 slot
    w1f[i] = f;
  }
  bf16x8 w2f[4]; bf16x4 c2p[4];
#pragma unroll
  for (int i = 0; i < 4; ++i) {
    bf16x8 f;
#pragma unroll
    for (int j = 0; j < 4; ++j) f[j]     = bfr(W2[i * 512 + (4 * g + j) * 16 + n]);
#pragma unroll
    for (int j = 0; j < 4; ++j) f[4 + j] = bfr(W2[i * 512 + (16 + 4 * g + j) * 16 + n]);
    w2f[i] = f;
#pragma unroll
    for (int r = 0; r < 4; ++r) c2p[i][r] = bfr(b2[i * 16 + 4 * g + r]);
  }
  bf16x8 w3f[2]; bf16x4 c3p[2];
#pragma unroll
  for (int i = 0; i < 2; ++i) {
    bf16x8 f;
#pragma unroll
    for (int j = 0; j < 4; ++j) f[j]     = bfr(W3[i * 512 + (4 * g + j) * 16 + n]);
#pragma unroll
    for (int j = 0; j < 4; ++j) f[4 + j] = bfr(W3[i * 512 + (16 + 4 * g + j) * 16 + n]);
    w3f[i] = f;
#pragma unroll
    for (int r = 0; r < 4; ++r) c3p[i][r] = bfr(b3[i * 16 + 4 * g + r]);
  }
  bf16x8 w4f; bf16x4 c4p;
  {
    bf16x8 f;
#pragma unroll
    for (int j = 0; j < 4; ++j) f[j]     = bfr(W4[(4 * g + j) * 16 + n]);
#pragma unroll
    for (int j = 0; j < 4; ++j) f[4 + j] = bfr(W4[(16 + 4 * g + j) * 16 + n]);
    w4f = f;
#pragma unroll
    for (int r = 0; r < 4; ++r) c4p[r] = bfr(b4[4 * g + r]);
  }

  const short bias_slot = (g == 0) ? bfr(1.0f) : (short)0;
  const f32x4* __restrict__ xf = reinterpret_cast<const f32x4*>(x);
  f32x4* __restrict__ of = reinterpret_cast<f32x4*>(out);

  int t = gw;
  if (t >= ntiles) return;

  // lane (n,g) owns sample row 16t+n, features [4g,4g+3] -> one 16B load
  f32x4 xa = xf[(size_t)(t * 16 + n) * 4 + g];
  f32x4 xb1 = xa;
  if (t + nw < ntiles) xb1 = xf[(size_t)((t + nw) * 16 + n) * 4 + g];

  for (; t < ntiles; t += nw) {
    f32x4 xc = xb1;
    if (t + 2 * nw < ntiles) xc = xf[(size_t)((t + 2 * nw) * 16 + n) * 4 + g];

    // level-1 B fragment: x^T with constant-1 bias feature at k==16
    bf16x8 xbf;
    xbf[0] = bfr(xa[0]); xbf[1] = bfr(xa[1]);
    xbf[2] = bfr(xa[2]); xbf[3] = bfr(xa[3]);
    xbf[4] = bias_slot; xbf[5] = 0; xbf[6] = 0; xbf[7] = 0;

    const f32x4 zero = {0.f, 0.f, 0.f, 0.f};

    // DFS evaluation: at most 2 of each level's accumulators live at once.
    f32x4 a2_0, a2_1, a3_0, a3_1;

#pragma unroll
    for (int half = 0; half < 2; ++half) {
      // L1 nodes {4h,4h+1} -> L2 node 2h ; L1 nodes {4h+2,4h+3} -> L2 node 2h+1
#pragma unroll
      for (int q = 0; q < 2; ++q) {
        const int li = 4 * half + 2 * q;      // first L1 node of the pair
        f32x4 aL = __builtin_amdgcn_mfma_f32_16x16x32_bf16(w1f[li],     xbf, zero, 0, 0, 0);
        f32x4 aR = __builtin_amdgcn_mfma_f32_16x16x32_bf16(w1f[li + 1], xbf, zero, 0, 0, 0);
        bf16x8 hb;
#pragma unroll
        for (int r = 0; r < 4; ++r) {
          hb[r]     = bfr(relu_(aL[r]));
          hb[4 + r] = bfr(relu_(aR[r]));
        }
        const int l2i = 2 * half + q;
        f32x4 acc = __builtin_amdgcn_mfma_f32_16x16x32_bf16(w2f[l2i], hb, unpk(c2p[l2i]), 0, 0, 0);
        if (q == 0) a2_0 = acc; else a2_1 = acc;
      }
      bf16x8 hb3;
#pragma unroll
      for (int r = 0; r < 4; ++r) {
        hb3[r]     = bfr(relu_(a2_0[r]));
        hb3[4 + r] = bfr(relu_(a2_1[r]));
      }
      f32x4 acc3 = __builtin_amdgcn_mfma_f32_16x16x32_bf16(w3f[half], hb3, unpk(c3p[half]), 0, 0, 0);
      if (half == 0) a3_0 = acc3; else a3_1 = acc3;
    }

    bf16x8 hb4;
#pragma unroll
    for (int r = 0; r < 4; ++r) {
      hb4[r]     = bfr(relu_(a3_0[r]));
      hb4[4 + r] = bfr(relu_(a3_1[r]));
    }
    f32x4 a4 = __builtin_amdgcn_mfma_f32_16x16x32_bf16(w4f, hb4, unpk(c4p), 0, 0, 0);

    f32x4 o;
#pragma unroll
    for (int r = 0; r < 4; ++r) o[r] = relu_(a4[r]);
    __builtin_nontemporal_store(o, &of[(size_t)(t * 16 + n) * 4 + g]);

    xa = xb1;
    xb1 = xc;
  }
}

extern "C" void kernel_launch(void* const* d_in, const int* in_sizes, int n_in,
                              void* d_out, int out_size, void* d_ws, size_t ws_size,
                              hipStream_t stream) {
  const float* x  = (const float*)d_in[0];
  const float* W1 = (const float*)d_in[1];
  const float* b1 = (const float*)d_in[2];
  const float* W2 = (const float*)d_in[3];
  const float* b2 = (const float*)d_in[4];
  const float* W3 = (const float*)d_in[5];
  const float* b3 = (const float*)d_in[6];
  const float* W4 = (const float*)d_in[7];
  const float* b4 = (const float*)d_in[8];
  float* out = (float*)d_out;

  const int ntiles = in_sizes[0] / 256;   // 16 samples x 16 features per tile
  const int block = 256;                  // 4 waves/block
  const int grid = 1024;                  // exactly 4 blocks/CU resident
  tree_mlp_mfma5<<<grid, block, 0, stream>>>(x, W1, b1, W2, b2, W3, b3, W4, b4,
                                             out, ntiles);
}